// Round 7
// baseline (1525.708 us; speedup 1.0000x reference)
//
#include <hip/hip_runtime.h>
#include <hip/hip_fp16.h>
#include <cstddef>

// ---------------------------------------------------------------------------
// SpatialAudioRenderer on MI355X — v7: occupancy-restored MFMA pipeline.
//
// R6: conv2_final regressed (60.9KB LDS -> 2 blocks/CU, Occ 11.8%). v7:
//  - final tile 120 cols -> 8 N-tiles, 2/wave balanced; single-buffered A;
//    LDS phase-aliased to 39,936 B -> 4 blocks/CU target.
//  - stats: waves split M x N 2x2 (B-read feeds 4 MFMAs, half the LDS reads),
//    shuffle-reduce epilogue.
// ---------------------------------------------------------------------------

#define TLEN 131072
#define NB 8
#define NICH 2
#define NHID 64
#define NH2 128
#define EPSV 1e-5f
#define CNTF 1048576.0f  // NB * TLEN
#define FT 120           // final-kernel output tile
#define FGRID 1093       // ceil(TLEN / FT)

typedef _Float16 f16x8 __attribute__((ext_vector_type(8)));
typedef float f32x4 __attribute__((ext_vector_type(4)));

__device__ __forceinline__ float lrelu(float v) { return v >= 0.f ? v : 0.2f * v; }
__device__ __forceinline__ unsigned short h16(float v) {
  return __half_as_ushort(__float2half(v));
}
__device__ __forceinline__ float fh16(unsigned short u) {
  return __half2float(__ushort_as_half(u));
}

// ---------------------------------------------------------------------------
// Kernel 0: weight prep.
//  w2sp/w2re: [o][K=tap*64+ch] fp16, 128x448.
//  w3g:       [m=oc*7+tap][ch] fp16, 16x128 (rows 14,15 zero), from RW3.
// ---------------------------------------------------------------------------
__global__ __launch_bounds__(256) void prep_weights(
    const float* __restrict__ W2c, const float* __restrict__ RW2c,
    const float* __restrict__ RW3c,
    unsigned short* __restrict__ w2sp, unsigned short* __restrict__ w2re,
    unsigned short* __restrict__ w3g)
{
  int e = blockIdx.x * 256 + threadIdx.x;
  if (e < 57344) {
    int o = e / 448, K = e % 448;
    w2sp[e] = h16(W2c[(o * 64 + (K & 63)) * 7 + (K >> 6)]);
  } else if (e < 114688) {
    int e2 = e - 57344;
    int o = e2 / 448, K = e2 % 448;
    w2re[e2] = h16(RW2c[(o * 64 + (K & 63)) * 7 + (K >> 6)]);
  } else if (e < 116736) {
    int e2 = e - 114688;
    int m = e2 >> 7, ch = e2 & 127;
    w3g[e2] = (m < 14) ? h16(RW3c[((m / 7) * 128 + ch) * 7 + (m % 7)])
                       : (unsigned short)0;
  }
}

// ---------------------------------------------------------------------------
// Kernel 1/7: conv1 (Cin=2, Cout=64, K=7, SAME) -> per-block channel sum/sumsq.
// ---------------------------------------------------------------------------
#define TCH1 1024
__global__ __launch_bounds__(256) void conv1_stats(
    const float* __restrict__ x, const float* __restrict__ W,
    const float* __restrict__ bias, float* __restrict__ partials)
{
  const int b = blockIdx.x >> 7;
  const int t0 = (blockIdx.x & 127) * TCH1;
  __shared__ float xs[2 * 1032];
  __shared__ float red[512];

  for (int i = 0; i < 2; ++i)
    for (int j = threadIdx.x; j < TCH1 + 6; j += 256) {
      int tg = t0 - 3 + j;
      xs[i * 1032 + j] = (tg >= 0 && tg < TLEN) ? x[(b * NICH + i) * TLEN + tg] : 0.f;
    }
  __syncthreads();

  const int o = threadIdx.x & 63;
  const int sub = threadIdx.x >> 6;
  float w[14];
  #pragma unroll
  for (int j = 0; j < 14; ++j) w[j] = W[o * 14 + j];
  const float bo = bias[o];

  float s = 0.f, ss = 0.f;
  const int tbeg = sub * (TCH1 / 4), tend = tbeg + TCH1 / 4;
  for (int tt = tbeg; tt < tend; tt += 4) {
    float a4[2][10];
    #pragma unroll
    for (int i = 0; i < 2; ++i) {
      const float* xp = &xs[i * 1032 + tt];
      float4 v0 = *reinterpret_cast<const float4*>(xp);
      float4 v1 = *reinterpret_cast<const float4*>(xp + 4);
      float2 v2 = *reinterpret_cast<const float2*>(xp + 8);
      a4[i][0] = v0.x; a4[i][1] = v0.y; a4[i][2] = v0.z; a4[i][3] = v0.w;
      a4[i][4] = v1.x; a4[i][5] = v1.y; a4[i][6] = v1.z; a4[i][7] = v1.w;
      a4[i][8] = v2.x; a4[i][9] = v2.y;
    }
    #pragma unroll
    for (int tq = 0; tq < 4; ++tq) {
      float acc = bo;
      #pragma unroll
      for (int i = 0; i < 2; ++i)
        #pragma unroll
        for (int k = 0; k < 7; ++k)
          acc += a4[i][tq + k] * w[i * 7 + k];
      s += acc; ss += acc * acc;
    }
  }
  red[o * 4 + sub] = s;
  red[(64 + o) * 4 + sub] = ss;
  __syncthreads();
  if (threadIdx.x < 128) {
    const float* r = &red[threadIdx.x * 4];
    partials[blockIdx.x * 128 + threadIdx.x] = r[0] + r[1] + r[2] + r[3];
  }
}

// ---------------------------------------------------------------------------
// Kernel 2: reduce partials -> bn affine coefs.
// ---------------------------------------------------------------------------
__global__ __launch_bounds__(256) void reduce_coef(
    const float* __restrict__ partials, int nblocks, int C,
    const float* __restrict__ g, const float* __restrict__ be,
    float* __restrict__ coef)
{
  const int c = blockIdx.x;
  float s = 0.f, ss = 0.f;
  for (int j = threadIdx.x; j < nblocks; j += 256) {
    s  += partials[j * 2 * C + c];
    ss += partials[j * 2 * C + C + c];
  }
  #pragma unroll
  for (int off = 32; off >= 1; off >>= 1) {
    s  += __shfl_down(s, off, 64);
    ss += __shfl_down(ss, off, 64);
  }
  __shared__ float rs[4], rss[4];
  const int lane = threadIdx.x & 63, wv = threadIdx.x >> 6;
  if (lane == 0) { rs[wv] = s; rss[wv] = ss; }
  __syncthreads();
  if (threadIdx.x == 0) {
    float st  = rs[0] + rs[1] + rs[2] + rs[3];
    float sst = rss[0] + rss[1] + rss[2] + rss[3];
    float mean = st / CNTF;
    float var  = sst / CNTF - mean * mean;
    float a = g[c] * rsqrtf(var + EPSV);
    coef[c] = a;
    coef[C + c] = be[c] - mean * a;
  }
}

// ---------------------------------------------------------------------------
// Shared h1 helpers (see v6). h1f row r <-> t = t0 - HOF + r; xs col j <->
// t = t0 - HOF - 3 + j.
// ---------------------------------------------------------------------------
template<int CPT, int RMAX, int HOF>
__device__ __forceinline__ void h1_compute(
    int t0, const float* xs, const float* w1T,
    const float* __restrict__ coef1, const float* __restrict__ b1c,
    unsigned short* h1f)
{
  const int cgr = threadIdx.x & 15, cg2 = threadIdx.x >> 4;
  const int ch0 = cgr * 4;
  float wreg[4][14];
  #pragma unroll
  for (int q = 0; q < 14; ++q)
    #pragma unroll
    for (int cq = 0; cq < 4; ++cq)
      wreg[cq][q] = w1T[q * 64 + ch0 + cq];
  float a1v[4], d1v[4], b1v[4];
  #pragma unroll
  for (int cq = 0; cq < 4; ++cq) {
    a1v[cq] = coef1[ch0 + cq];
    d1v[cq] = coef1[64 + ch0 + cq];
    b1v[cq] = b1c[ch0 + cq];
  }
  const int r0 = cg2 * CPT;
  float xv[2][16];
  #pragma unroll
  for (int i2 = 0; i2 < 2; ++i2) {
    const float* xp = &xs[i2 * 168 + r0];
    float4 p0 = *reinterpret_cast<const float4*>(xp);
    float4 p1 = *reinterpret_cast<const float4*>(xp + 4);
    float4 p2 = *reinterpret_cast<const float4*>(xp + 8);
    float4 p3 = *reinterpret_cast<const float4*>(xp + 12);
    xv[i2][0] = p0.x;  xv[i2][1] = p0.y;  xv[i2][2] = p0.z;  xv[i2][3] = p0.w;
    xv[i2][4] = p1.x;  xv[i2][5] = p1.y;  xv[i2][6] = p1.z;  xv[i2][7] = p1.w;
    xv[i2][8] = p2.x;  xv[i2][9] = p2.y;  xv[i2][10] = p2.z; xv[i2][11] = p2.w;
    xv[i2][12] = p3.x; xv[i2][13] = p3.y; xv[i2][14] = p3.z; xv[i2][15] = p3.w;
  }
  #pragma unroll
  for (int cc = 0; cc < CPT; ++cc) {
    int r = r0 + cc;
    if (r < RMAX) {
      int t = t0 - HOF + r;
      bool ok = (t >= 0) && (t < TLEN);
      unsigned us[4];
      #pragma unroll
      for (int cq = 0; cq < 4; ++cq) {
        float acc = b1v[cq];
        #pragma unroll
        for (int i2 = 0; i2 < 2; ++i2)
          #pragma unroll
          for (int k = 0; k < 7; ++k)
            acc += xv[i2][cc + k] * wreg[cq][i2 * 7 + k];
        float v = lrelu(a1v[cq] * acc + d1v[cq]);
        us[cq] = h16(ok ? v : 0.f);
      }
      *(uint2*)(h1f + r * 72 + ch0) =
          make_uint2(us[0] | (us[1] << 16), us[2] | (us[3] << 16));
    }
  }
}

__device__ __forceinline__ void stage_x_w1(
    int t0, int xoff, const float* __restrict__ xin, int b,
    const float* __restrict__ W1c, float* xs, float* w1T)
{
  for (int e = threadIdx.x; e < 2 * 168; e += 256) {
    int i = e / 168, j = e % 168;
    int tg = t0 - xoff + j;
    xs[e] = (tg >= 0 && tg < TLEN) ? xin[(b * NICH + i) * TLEN + tg] : 0.f;
  }
  for (int e = threadIdx.x; e < 14 * 64; e += 256) {
    int q = e >> 6, ch = e & 63;
    w1T[e] = W1c[ch * 14 + q];
  }
}

// ---------------------------------------------------------------------------
// Kernel 3/9: conv2 via fp16 MFMA, stats only. 128 o x 128 t per block.
// Waves split M x N 2x2: wave owns 4 M-tiles x 4 N-tiles (B-read -> 4 MFMAs).
// Epilogue: shuffle-reduce over mn + tiny red2 buffer.
// ---------------------------------------------------------------------------
__global__ __launch_bounds__(256) void conv2_stats_mfma(
    const float* __restrict__ xin,
    const float* __restrict__ W1c, const float* __restrict__ b1c,
    const float* __restrict__ coef1,
    const unsigned short* __restrict__ w2f,
    const float* __restrict__ b2c,
    float* __restrict__ partials)
{
  const int b  = blockIdx.x >> 10;
  const int t0 = (blockIdx.x & 1023) * 128;

  __shared__ __align__(16) char smem[24224];
  unsigned short* h1f = (unsigned short*)smem;   // [134][72], r <-> t0-3+r
  float* xs   = (float*)(smem + 19296);          // [2][168], j <-> t0-6+j
  float* w1T  = (float*)(smem + 20640);          // [14][64]
  float* red2 = (float*)smem;                    // [2][2][64] S + same SS (late)

  stage_x_w1(t0, 6, xin, b, W1c, xs, w1T);
  __syncthreads();
  h1_compute<9, 134, 3>(t0, xs, w1T, coef1, b1c, h1f);
  __syncthreads();

  const int lane = threadIdx.x & 63;
  const int wv = threadIdx.x >> 6;
  const int mn = lane & 15, quad = lane >> 4;
  const int mh = wv & 1, nh = wv >> 1;
  const int o0w = mh * 64;

  f32x4 acc[4][4];
  #pragma unroll
  for (int m = 0; m < 4; ++m)
    #pragma unroll
    for (int ni = 0; ni < 4; ++ni) {
      f32x4 z = {0.f, 0.f, 0.f, 0.f};
      acc[m][ni] = z;
    }

  f16x8 Ac[4];
  #pragma unroll
  for (int c = 0; c < 14; ++c) {
    #pragma unroll
    for (int m = 0; m < 4; ++m)
      Ac[m] = *(const f16x8*)(w2f + (o0w + m * 16 + mn) * 448 + c * 32 + quad * 8);
    const int tap = c >> 1;
    const int ch0 = (c & 1) * 32 + quad * 8;
    #pragma unroll
    for (int ni = 0; ni < 4; ++ni) {
      const int row = (nh * 4 + ni) * 16 + mn + tap;
      f16x8 bb = *(const f16x8*)(h1f + row * 72 + ch0);
      #pragma unroll
      for (int m = 0; m < 4; ++m)
        acc[m][ni] = __builtin_amdgcn_mfma_f32_16x16x32_f16(Ac[m], bb, acc[m][ni], 0, 0, 0);
    }
  }

  // per-lane sums over this wave's 4 N-tiles, then shuffle-reduce over mn
  float sv[4][4], ssv[4][4];
  #pragma unroll
  for (int m = 0; m < 4; ++m)
    #pragma unroll
    for (int r = 0; r < 4; ++r) {
      float bo = b2c[o0w + m * 16 + quad * 4 + r];
      float s = 0.f, ss = 0.f;
      #pragma unroll
      for (int ni = 0; ni < 4; ++ni) {
        float v = acc[m][ni][r] + bo;
        s += v; ss += v * v;
      }
      sv[m][r] = s; ssv[m][r] = ss;
    }
  #pragma unroll
  for (int msk = 1; msk <= 8; msk <<= 1)
    #pragma unroll
    for (int m = 0; m < 4; ++m)
      #pragma unroll
      for (int r = 0; r < 4; ++r) {
        sv[m][r]  += __shfl_xor(sv[m][r],  msk, 64);
        ssv[m][r] += __shfl_xor(ssv[m][r], msk, 64);
      }
  __syncthreads();   // h1f dead; red2 aliases
  if (mn == 0) {
    #pragma unroll
    for (int m = 0; m < 4; ++m)
      #pragma unroll
      for (int r = 0; r < 4; ++r) {
        int op = m * 16 + quad * 4 + r;
        red2[(mh * 2 + nh) * 64 + op] = sv[m][r];
        red2[256 + (mh * 2 + nh) * 64 + op] = ssv[m][r];
      }
  }
  __syncthreads();
  {
    int tid = threadIdx.x;
    if (tid < 256) {
      int which = tid >> 7;            // 0 = sum, 1 = sumsq
      int o = tid & 127;
      int base = which * 256 + (o >> 6) * 128 + (o & 63);
      float s = red2[base] + red2[base + 64];
      partials[blockIdx.x * 256 + which * 128 + o] = s;
    }
  }
}

// ---------------------------------------------------------------------------
// Kernel 5: fp32 recompute of c2 head + bn2 + conv3(t=0) + tanh -> HRTF gather.
// ---------------------------------------------------------------------------
__global__ __launch_bounds__(256) void finalize_spatial(
    const float* __restrict__ x,
    const float* __restrict__ W1c, const float* __restrict__ b1c,
    const float* __restrict__ coef1,
    const float* __restrict__ W2c, const float* __restrict__ b2c,
    const float* __restrict__ coef2,
    const float* __restrict__ W3c, const float* __restrict__ b3c,
    const float* __restrict__ hrtf, float* __restrict__ wgbuf)
{
  __shared__ float xl[NB * 2 * 16];
  __shared__ float h1l[NB * 64 * 10];
  __shared__ float h2l[NB * NH2 * 4];
  __shared__ float sp[48];
  const int tid = threadIdx.x;
  {
    int bb = tid >> 5, i = (tid >> 4) & 1, j = tid & 15;
    int t = j - 6;
    xl[tid] = (t >= 0) ? x[(bb * 2 + i) * TLEN + t] : 0.f;
  }
  __syncthreads();
  for (int e = tid; e < NB * 64; e += 256) {
    int bb = e >> 6, ch = e & 63;
    float a1 = coef1[ch], d1 = coef1[64 + ch], bo = b1c[ch];
    for (int tt = 0; tt < 10; ++tt) {
      float acc = bo;
      #pragma unroll
      for (int i2 = 0; i2 < 2; ++i2)
        #pragma unroll
        for (int k = 0; k < 7; ++k)
          acc += xl[(bb * 2 + i2) * 16 + tt + k] * W1c[ch * 14 + i2 * 7 + k];
      float v = lrelu(a1 * acc + d1);
      h1l[(bb * 64 + ch) * 10 + tt] = (tt >= 3) ? v : 0.f;
    }
  }
  __syncthreads();
  for (int e = tid; e < NB * NH2; e += 256) {
    int bb = e >> 7, o = e & 127;
    float a2 = coef2[o], d2 = coef2[NH2 + o], bo = b2c[o];
    float acc[4] = {bo, bo, bo, bo};
    for (int i = 0; i < 64; ++i)
      #pragma unroll
      for (int k = 0; k < 7; ++k) {
        float w = W2c[(o * 64 + i) * 7 + k];
        #pragma unroll
        for (int t = 0; t < 4; ++t)
          acc[t] += h1l[(bb * 64 + i) * 10 + t + k] * w;
      }
    #pragma unroll
    for (int t = 0; t < 4; ++t)
      h2l[(bb * NH2 + o) * 4 + t] = lrelu(a2 * acc[t] + d2);
  }
  __syncthreads();
  if (tid < 48) {
    int bb = tid / 6, c3 = tid % 6;
    float acc = b3c[c3];
    for (int c = 0; c < NH2; ++c)
      #pragma unroll
      for (int k = 3; k < 7; ++k)
        acc += h2l[(bb * NH2 + c) * 4 + (k - 3)] * W3c[(c3 * NH2 + c) * 7 + k];
    sp[tid] = tanhf(acc);
  }
  __syncthreads();
  if (tid < 16) {
    int bb = tid >> 1, i = tid & 1;
    float az = (sp[bb * 6 + i * 3 + 0] + 1.f) * 0.5f * 11.f;
    float el = (sp[bb * 6 + i * 3 + 1] + 1.f) * 0.5f * 4.f;
    float dist = (sp[bb * 6 + i * 3 + 2] + 1.f) * 0.5f * 0.9f + 0.1f;
    int azi = min(max((int)az, 0), 11);
    int eli = min(max((int)el, 0), 4);
    int idx = eli * 12 + azi;
    for (int e = 0; e < 14; ++e)
      wgbuf[(bb * 2 + i) * 14 + e] = hrtf[idx * 14 + e] * dist;
  }
}

// ---------------------------------------------------------------------------
// Kernel 6: summed[b,c,t] = sum_{i,k} x[b,i,t+k-3] * wg[b,i,c,k]
// ---------------------------------------------------------------------------
__global__ __launch_bounds__(256) void mix_kernel(
    const float* __restrict__ x, const float* __restrict__ wgbuf,
    float* __restrict__ summed)
{
  const int b = blockIdx.x >> 7;
  const int t0 = (blockIdx.x & 127) * 1024 + threadIdx.x * 4;
  float wv[2][2][7];
  #pragma unroll
  for (int i = 0; i < 2; ++i)
    #pragma unroll
    for (int c = 0; c < 2; ++c)
      #pragma unroll
      for (int k = 0; k < 7; ++k)
        wv[i][c][k] = wgbuf[(b * 2 + i) * 14 + c * 7 + k];
  float acc[2][4] = {{0.f, 0.f, 0.f, 0.f}, {0.f, 0.f, 0.f, 0.f}};
  #pragma unroll
  for (int i = 0; i < 2; ++i) {
    float xl[12];
    #pragma unroll
    for (int j = 0; j < 12; ++j) {
      int tg = t0 - 4 + j;
      xl[j] = (tg >= 0 && tg < TLEN) ? x[(b * 2 + i) * TLEN + tg] : 0.f;
    }
    #pragma unroll
    for (int c = 0; c < 2; ++c)
      #pragma unroll
      for (int k = 0; k < 7; ++k)
        #pragma unroll
        for (int tt = 0; tt < 4; ++tt)
          acc[c][tt] += xl[tt + k + 1] * wv[i][c][k];
  }
  #pragma unroll
  for (int c = 0; c < 2; ++c)
    *reinterpret_cast<float4*>(&summed[(b * 2 + c) * TLEN + t0]) =
        make_float4(acc[c][0], acc[c][1], acc[c][2], acc[c][3]);
}

// ---------------------------------------------------------------------------
// Kernel 11: 120-col tile, grid (1093, NB). h1 fp16 -> conv2 MFMA (2 N-tiles
// per wave, 8 M-tiles, single-buffered A) -> bn2+lrelu -> h2t fp16 [col][ch]
// (aliases dead h1f/xs) -> conv3 MFMA (K=ch) -> dq -> 7-tap gather + tanh.
// LDS 39,936 B -> target 4 blocks/CU.
// ---------------------------------------------------------------------------
__global__ __launch_bounds__(256) void conv2_final_mfma(
    const float* __restrict__ xin,
    const float* __restrict__ W1c, const float* __restrict__ b1c,
    const float* __restrict__ coef1,
    const unsigned short* __restrict__ w2f,
    const float* __restrict__ b2c, const float* __restrict__ coef2,
    const unsigned short* __restrict__ w3g, const float* __restrict__ rb3c,
    float* __restrict__ out)
{
  const int b  = blockIdx.y;
  const int t0 = blockIdx.x * FT;

  __shared__ __align__(16) char smem[39936];
  float* xs  = (float*)smem;                             // [2][168], j <-> t0-9+j
  float* w1T = (float*)(smem + 1344);                    // [14][64]
  unsigned short* h1f = (unsigned short*)(smem + 4928);  // [134][72], r <-> t0-6+r
  unsigned short* h2t = (unsigned short*)smem;           // [128][136] (late alias)
  unsigned short* dq  = (unsigned short*)(smem + 34816); // [128][20]

  stage_x_w1(t0, 9, xin, b, W1c, xs, w1T);
  __syncthreads();
  h1_compute<9, 134, 6>(t0, xs, w1T, coef1, b1c, h1f);
  __syncthreads();

  const int lane = threadIdx.x & 63;
  const int wv = threadIdx.x >> 6;
  const int mn = lane & 15, quad = lane >> 4;
  const int nt0 = wv * 2;

  // ---- conv2: 14 K-chunks x 2 N-tiles x 8 M-tiles per wave ----
  f32x4 acc[8][2];
  #pragma unroll
  for (int mt = 0; mt < 8; ++mt)
    #pragma unroll
    for (int i = 0; i < 2; ++i) {
      f32x4 z = {0.f, 0.f, 0.f, 0.f};
      acc[mt][i] = z;
    }

  f16x8 Ac[8];
  #pragma unroll
  for (int c = 0; c < 14; ++c) {
    #pragma unroll
    for (int mt = 0; mt < 8; ++mt)
      Ac[mt] = *(const f16x8*)(w2f + (mt * 16 + mn) * 448 + c * 32 + quad * 8);
    const int tap = c >> 1;
    const int ch0 = (c & 1) * 32 + quad * 8;
    #pragma unroll
    for (int i = 0; i < 2; ++i) {
      f16x8 bb = *(const f16x8*)(h1f + ((nt0 + i) * 16 + mn + tap) * 72 + ch0);
      #pragma unroll
      for (int mt = 0; mt < 8; ++mt)
        acc[mt][i] = __builtin_amdgcn_mfma_f32_16x16x32_f16(Ac[mt], bb, acc[mt][i], 0, 0, 0);
    }
  }
  __syncthreads();   // h1f/xs/w1T dead; h2t aliases them

  // ---- bn2 + lrelu -> h2t fp16 [j'][ch]; j' <-> t = t0-3+j' ----
  #pragma unroll
  for (int i = 0; i < 2; ++i) {
    int jp = (nt0 + i) * 16 + mn;
    int t = t0 - 3 + jp;
    bool ok = (t >= 0) && (t < TLEN);
    #pragma unroll
    for (int mt = 0; mt < 8; ++mt) {
      unsigned us[4];
      #pragma unroll
      for (int r = 0; r < 4; ++r) {
        int o = mt * 16 + quad * 4 + r;
        float v = acc[mt][i][r] + b2c[o];
        v = lrelu(coef2[o] * v + coef2[NH2 + o]);
        us[r] = h16(ok ? v : 0.f);
      }
      *(uint2*)(h2t + jp * 136 + mt * 16 + quad * 4) =
          make_uint2(us[0] | (us[1] << 16), us[2] | (us[3] << 16));
    }
  }
  __syncthreads();

  // ---- conv3: D'[m=oc*7+tap][n=j'] = sum_ch W3 * h2 ----
  f32x4 acc3[2];
  #pragma unroll
  for (int i = 0; i < 2; ++i) {
    f32x4 z = {0.f, 0.f, 0.f, 0.f};
    acc3[i] = z;
  }
  #pragma unroll
  for (int c = 0; c < 4; ++c) {
    f16x8 A3 = *(const f16x8*)(w3g + mn * 128 + c * 32 + quad * 8);
    #pragma unroll
    for (int i = 0; i < 2; ++i) {
      f16x8 bb = *(const f16x8*)(h2t + ((nt0 + i) * 16 + mn) * 136 + c * 32 + quad * 8);
      acc3[i] = __builtin_amdgcn_mfma_f32_16x16x32_f16(A3, bb, acc3[i], 0, 0, 0);
    }
  }
  #pragma unroll
  for (int i = 0; i < 2; ++i) {
    int n = (nt0 + i) * 16 + mn;
    unsigned us[4];
    #pragma unroll
    for (int r = 0; r < 4; ++r) us[r] = h16(acc3[i][r]);
    *(uint2*)(dq + n * 20 + quad * 4) =
        make_uint2(us[0] | (us[1] << 16), us[2] | (us[3] << 16));
  }
  __syncthreads();

  // ---- gather: out[oc][u] = tanh(b3 + sum_tap D'[u+tap][oc*7+tap]) ----
  {
    int tid = threadIdx.x;
    if (tid < 240) {
      int oc = (tid >= FT) ? 1 : 0;
      int u = tid - oc * FT;
      float s = rb3c[oc];
      #pragma unroll
      for (int tap = 0; tap < 7; ++tap)
        s += fh16(dq[(u + tap) * 20 + oc * 7 + tap]);
      int t = t0 + u;
      if (t < TLEN) out[(b * 2 + oc) * TLEN + t] = tanhf(s);
    }
  }
}

// ---------------------------------------------------------------------------
extern "C" void kernel_launch(void* const* d_in, const int* in_sizes, int n_in,
                              void* d_out, int out_size, void* d_ws, size_t ws_size,
                              hipStream_t stream)
{
  (void)in_sizes; (void)n_in; (void)out_size; (void)ws_size;
  const float* x    = (const float*)d_in[0];
  const float* W1   = (const float*)d_in[1];
  const float* b1   = (const float*)d_in[2];
  const float* g1   = (const float*)d_in[3];
  const float* be1  = (const float*)d_in[4];
  const float* W2   = (const float*)d_in[5];
  const float* b2   = (const float*)d_in[6];
  const float* g2   = (const float*)d_in[7];
  const float* be2  = (const float*)d_in[8];
  const float* W3   = (const float*)d_in[9];
  const float* b3   = (const float*)d_in[10];
  const float* hrtf = (const float*)d_in[11];
  const float* RW1  = (const float*)d_in[12];
  const float* rb1  = (const float*)d_in[13];
  const float* rg1  = (const float*)d_in[14];
  const float* rbe1 = (const float*)d_in[15];
  const float* RW2  = (const float*)d_in[16];
  const float* rb2  = (const float*)d_in[17];
  const float* rg2  = (const float*)d_in[18];
  const float* rbe2 = (const float*)d_in[19];
  const float* RW3  = (const float*)d_in[20];
  const float* rb3  = (const float*)d_in[21];
  float* out = (float*)d_out;

  // d_out doubles as the 8192x256-f stats-partials buffer (lifetime ends
  // before conv2_final_mfma writes output).
  float* partialsB = (float*)d_out;

  char* ws = (char*)d_ws;
  float* partialsA      = (float*)(ws + 0);        // 524,288 B
  float* summed         = (float*)(ws + 524288);   // 8,388,608 B
  float* coef1          = (float*)(ws + 8912896);  // 128 f
  float* coef2          = (float*)(ws + 8913408);  // 256 f
  float* coefR1         = (float*)(ws + 8914432);  // 128 f
  float* coefR2         = (float*)(ws + 8914944);  // 256 f
  float* wgbuf          = (float*)(ws + 8915968);  // 224 f
  unsigned short* w2sp  = (unsigned short*)(ws + 8916992);  // 114,688 B
  unsigned short* w2re  = (unsigned short*)(ws + 9031680);  // 114,688 B
  unsigned short* w3g   = (unsigned short*)(ws + 9146368);  // 4,096 B
  // total ws use: 9,150,464 bytes

  prep_weights<<<456, 256, 0, stream>>>(W2, RW2, RW3, w2sp, w2re, w3g);
  // ---- spatial parameter network ----
  conv1_stats<<<1024, 256, 0, stream>>>(x, W1, b1, partialsA);
  reduce_coef<<<64, 256, 0, stream>>>(partialsA, 1024, 64, g1, be1, coef1);
  conv2_stats_mfma<<<8192, 256, 0, stream>>>(x, W1, b1, coef1, w2sp, b2, partialsB);
  reduce_coef<<<128, 256, 0, stream>>>(partialsB, 8192, 128, g2, be2, coef2);
  finalize_spatial<<<1, 256, 0, stream>>>(x, W1, b1, coef1, W2, b2, coef2,
                                          W3, b3, hrtf, wgbuf);
  // ---- HRTF mixing ----
  mix_kernel<<<1024, 256, 0, stream>>>(x, wgbuf, summed);
  // ---- binaural renderer ----
  conv1_stats<<<1024, 256, 0, stream>>>(summed, RW1, rb1, partialsA);
  reduce_coef<<<64, 256, 0, stream>>>(partialsA, 1024, 64, rg1, rbe1, coefR1);
  conv2_stats_mfma<<<8192, 256, 0, stream>>>(summed, RW1, rb1, coefR1,
                                             w2re, rb2, partialsB);
  reduce_coef<<<128, 256, 0, stream>>>(partialsB, 8192, 128, rg2, rbe2, coefR2);
  conv2_final_mfma<<<dim3(FGRID, NB), 256, 0, stream>>>(
      summed, RW1, rb1, coefR1, w2re, rb2, coefR2, w3g, rb3, out);
}

// Round 8
// 972.452 us; speedup vs baseline: 1.5689x; 1.5689x over previous
//
#include <hip/hip_runtime.h>
#include <hip/hip_fp16.h>
#include <cstddef>

// ---------------------------------------------------------------------------
// SpatialAudioRenderer on MI355X — v8: coalesced A-fragments + VGPR diet.
//
// R7 post-mortem: occupancy was VGPR-limited (140 regs), not LDS; and A-loads
// were scatter-gathers (lane offsets (o)*448+c*32 -> 64 scattered 16B segs).
// v8: W2/W3 repacked fragment-contiguous ([c][mt] blocks of 1KB, lanes read
// contiguous); __launch_bounds__(256,4); Ac 4+4 split; h1 2-ch loop;
// stats kernel reverted to R6 mapping (prefetch + [128][17] reduce).
// ---------------------------------------------------------------------------

#define TLEN 131072
#define NB 8
#define NICH 2
#define NHID 64
#define NH2 128
#define EPSV 1e-5f
#define CNTF 1048576.0f  // NB * TLEN
#define FT 120           // final-kernel output tile
#define FGRID 1093       // ceil(TLEN / FT)

typedef _Float16 f16x8 __attribute__((ext_vector_type(8)));
typedef float f32x4 __attribute__((ext_vector_type(4)));

__device__ __forceinline__ float lrelu(float v) { return v >= 0.f ? v : 0.2f * v; }
__device__ __forceinline__ unsigned short h16(float v) {
  return __half_as_ushort(__float2half(v));
}
__device__ __forceinline__ float fh16(unsigned short u) {
  return __half2float(__ushort_as_half(u));
}

// ---------------------------------------------------------------------------
// Kernel 0: weight prep, fragment-contiguous layouts.
//  w2sp/w2re: frag = c*8+mt (c = tap*2 + (ch>=32), mt = o/16), 512 halfs each:
//             [frag*512 + (o%16)*32 + (ch%32)]  -> wave reads 1KB contiguous.
//  w3g:       [c*512 + m*32 + (ch%32)], m = oc*7+tap (rows 14,15 zero), c=ch/32.
// ---------------------------------------------------------------------------
__global__ __launch_bounds__(256) void prep_weights(
    const float* __restrict__ W2c, const float* __restrict__ RW2c,
    const float* __restrict__ RW3c,
    unsigned short* __restrict__ w2sp, unsigned short* __restrict__ w2re,
    unsigned short* __restrict__ w3g)
{
  int e = blockIdx.x * 256 + threadIdx.x;
  if (e < 114688) {
    int e2 = (e >= 57344) ? e - 57344 : e;
    int frag = e2 >> 9, within = e2 & 511;
    int c = frag >> 3, mt = frag & 7;
    int mn = within >> 5, kk = within & 31;
    int o = mt * 16 + mn;
    int tap = c >> 1, ch = (c & 1) * 32 + kk;
    const float* src = (e >= 57344) ? RW2c : W2c;
    unsigned short* dst = (e >= 57344) ? w2re : w2sp;
    dst[e2] = h16(src[(o * 64 + ch) * 7 + tap]);
  } else if (e < 116736) {
    int e2 = e - 114688;
    int c = e2 >> 9, within = e2 & 511;
    int m = within >> 5, kk = within & 31;
    int ch = c * 32 + kk;
    w3g[e2] = (m < 14) ? h16(RW3c[((m / 7) * 128 + ch) * 7 + (m % 7)])
                       : (unsigned short)0;
  }
}

// ---------------------------------------------------------------------------
// Kernel 1/7: conv1 (Cin=2, Cout=64, K=7, SAME) -> per-block channel sum/sumsq.
// ---------------------------------------------------------------------------
#define TCH1 1024
__global__ __launch_bounds__(256) void conv1_stats(
    const float* __restrict__ x, const float* __restrict__ W,
    const float* __restrict__ bias, float* __restrict__ partials)
{
  const int b = blockIdx.x >> 7;
  const int t0 = (blockIdx.x & 127) * TCH1;
  __shared__ float xs[2 * 1032];
  __shared__ float red[512];

  for (int i = 0; i < 2; ++i)
    for (int j = threadIdx.x; j < TCH1 + 6; j += 256) {
      int tg = t0 - 3 + j;
      xs[i * 1032 + j] = (tg >= 0 && tg < TLEN) ? x[(b * NICH + i) * TLEN + tg] : 0.f;
    }
  __syncthreads();

  const int o = threadIdx.x & 63;
  const int sub = threadIdx.x >> 6;
  float w[14];
  #pragma unroll
  for (int j = 0; j < 14; ++j) w[j] = W[o * 14 + j];
  const float bo = bias[o];

  float s = 0.f, ss = 0.f;
  const int tbeg = sub * (TCH1 / 4), tend = tbeg + TCH1 / 4;
  for (int tt = tbeg; tt < tend; tt += 4) {
    float a4[2][10];
    #pragma unroll
    for (int i = 0; i < 2; ++i) {
      const float* xp = &xs[i * 1032 + tt];
      float4 v0 = *reinterpret_cast<const float4*>(xp);
      float4 v1 = *reinterpret_cast<const float4*>(xp + 4);
      float2 v2 = *reinterpret_cast<const float2*>(xp + 8);
      a4[i][0] = v0.x; a4[i][1] = v0.y; a4[i][2] = v0.z; a4[i][3] = v0.w;
      a4[i][4] = v1.x; a4[i][5] = v1.y; a4[i][6] = v1.z; a4[i][7] = v1.w;
      a4[i][8] = v2.x; a4[i][9] = v2.y;
    }
    #pragma unroll
    for (int tq = 0; tq < 4; ++tq) {
      float acc = bo;
      #pragma unroll
      for (int i = 0; i < 2; ++i)
        #pragma unroll
        for (int k = 0; k < 7; ++k)
          acc += a4[i][tq + k] * w[i * 7 + k];
      s += acc; ss += acc * acc;
    }
  }
  red[o * 4 + sub] = s;
  red[(64 + o) * 4 + sub] = ss;
  __syncthreads();
  if (threadIdx.x < 128) {
    const float* r = &red[threadIdx.x * 4];
    partials[blockIdx.x * 128 + threadIdx.x] = r[0] + r[1] + r[2] + r[3];
  }
}

// ---------------------------------------------------------------------------
// Kernel 2: reduce partials -> bn affine coefs.
// ---------------------------------------------------------------------------
__global__ __launch_bounds__(256) void reduce_coef(
    const float* __restrict__ partials, int nblocks, int C,
    const float* __restrict__ g, const float* __restrict__ be,
    float* __restrict__ coef)
{
  const int c = blockIdx.x;
  float s = 0.f, ss = 0.f;
  for (int j = threadIdx.x; j < nblocks; j += 256) {
    s  += partials[j * 2 * C + c];
    ss += partials[j * 2 * C + C + c];
  }
  #pragma unroll
  for (int off = 32; off >= 1; off >>= 1) {
    s  += __shfl_down(s, off, 64);
    ss += __shfl_down(ss, off, 64);
  }
  __shared__ float rs[4], rss[4];
  const int lane = threadIdx.x & 63, wv = threadIdx.x >> 6;
  if (lane == 0) { rs[wv] = s; rss[wv] = ss; }
  __syncthreads();
  if (threadIdx.x == 0) {
    float st  = rs[0] + rs[1] + rs[2] + rs[3];
    float sst = rss[0] + rss[1] + rss[2] + rss[3];
    float mean = st / CNTF;
    float var  = sst / CNTF - mean * mean;
    float a = g[c] * rsqrtf(var + EPSV);
    coef[c] = a;
    coef[C + c] = be[c] - mean * a;
  }
}

// ---------------------------------------------------------------------------
// h1 helpers. h1f row r <-> t = t0 - HOF + r; xs col j <-> t = t0 - HOF - 3 + j.
// 2-channels-at-a-time to cut register high-water (28 w regs, not 56).
// ---------------------------------------------------------------------------
template<int CPT, int RMAX, int HOF>
__device__ __forceinline__ void h1_compute(
    int t0, const float* xs, const float* w1T,
    const float* __restrict__ coef1, const float* __restrict__ b1c,
    unsigned short* h1f)
{
  const int cgr = threadIdx.x & 15, cg2 = threadIdx.x >> 4;
  const int r0 = cg2 * CPT;
  float xv[2][16];
  #pragma unroll
  for (int i2 = 0; i2 < 2; ++i2) {
    const float* xp = &xs[i2 * 168 + r0];
    float4 p0 = *reinterpret_cast<const float4*>(xp);
    float4 p1 = *reinterpret_cast<const float4*>(xp + 4);
    float4 p2 = *reinterpret_cast<const float4*>(xp + 8);
    float4 p3 = *reinterpret_cast<const float4*>(xp + 12);
    xv[i2][0] = p0.x;  xv[i2][1] = p0.y;  xv[i2][2] = p0.z;  xv[i2][3] = p0.w;
    xv[i2][4] = p1.x;  xv[i2][5] = p1.y;  xv[i2][6] = p1.z;  xv[i2][7] = p1.w;
    xv[i2][8] = p2.x;  xv[i2][9] = p2.y;  xv[i2][10] = p2.z; xv[i2][11] = p2.w;
    xv[i2][12] = p3.x; xv[i2][13] = p3.y; xv[i2][14] = p3.z; xv[i2][15] = p3.w;
  }
  #pragma unroll
  for (int half = 0; half < 2; ++half) {
    const int chA = cgr * 4 + half * 2;
    float w0[14], w1[14];
    #pragma unroll
    for (int q = 0; q < 14; ++q) {
      w0[q] = w1T[q * 64 + chA];
      w1[q] = w1T[q * 64 + chA + 1];
    }
    const float a1A = coef1[chA],     d1A = coef1[64 + chA],     bA = b1c[chA];
    const float a1B = coef1[chA + 1], d1B = coef1[64 + chA + 1], bB = b1c[chA + 1];
    #pragma unroll
    for (int cc = 0; cc < CPT; ++cc) {
      int r = r0 + cc;
      if (r < RMAX) {
        int t = t0 - HOF + r;
        bool ok = (t >= 0) && (t < TLEN);
        float aA = bA, aB = bB;
        #pragma unroll
        for (int i2 = 0; i2 < 2; ++i2)
          #pragma unroll
          for (int k = 0; k < 7; ++k) {
            aA += xv[i2][cc + k] * w0[i2 * 7 + k];
            aB += xv[i2][cc + k] * w1[i2 * 7 + k];
          }
        float vA = lrelu(a1A * aA + d1A);
        float vB = lrelu(a1B * aB + d1B);
        unsigned uu = (unsigned)h16(ok ? vA : 0.f) |
                      ((unsigned)h16(ok ? vB : 0.f) << 16);
        *(unsigned*)(h1f + r * 72 + chA) = uu;
      }
    }
  }
}

__device__ __forceinline__ void stage_x_w1(
    int t0, int xoff, const float* __restrict__ xin, int b,
    const float* __restrict__ W1c, float* xs, float* w1T)
{
  for (int e = threadIdx.x; e < 2 * 168; e += 256) {
    int i = e / 168, j = e % 168;
    int tg = t0 - xoff + j;
    xs[e] = (tg >= 0 && tg < TLEN) ? xin[(b * NICH + i) * TLEN + tg] : 0.f;
  }
  for (int e = threadIdx.x; e < 14 * 64; e += 256) {
    int q = e >> 6, ch = e & 63;
    w1T[e] = W1c[ch * 14 + q];
  }
}

// ---------------------------------------------------------------------------
// Kernel 3/9: conv2 via fp16 MFMA, stats only. 128 o x 128 t per block.
// R6 mapping: wave w owns M-tiles {2w, 2w+1}, all 8 N-tiles; prefetched A
// (now coalesced); [128][17] LDS reduce epilogue.
// ---------------------------------------------------------------------------
__global__ __launch_bounds__(256, 4) void conv2_stats_mfma(
    const float* __restrict__ xin,
    const float* __restrict__ W1c, const float* __restrict__ b1c,
    const float* __restrict__ coef1,
    const unsigned short* __restrict__ w2f,
    const float* __restrict__ b2c,
    float* __restrict__ partials)
{
  const int b  = blockIdx.x >> 10;
  const int t0 = (blockIdx.x & 1023) * 128;

  __shared__ __align__(16) char smem[24224];
  unsigned short* h1f = (unsigned short*)smem;   // [134][72], r <-> t0-3+r
  float* xs   = (float*)(smem + 19296);          // [2][168], j <-> t0-6+j
  float* w1T  = (float*)(smem + 20640);          // [14][64]
  float* redS = (float*)smem;                    // [128][17] (aliases h1f, late)
  float* redSS= (float*)(smem + 8704);

  stage_x_w1(t0, 6, xin, b, W1c, xs, w1T);
  __syncthreads();
  h1_compute<9, 134, 3>(t0, xs, w1T, coef1, b1c, h1f);
  __syncthreads();

  const int lane = threadIdx.x & 63;
  const int wv = threadIdx.x >> 6;
  const int mn = lane & 15, quad = lane >> 4;

  f32x4 acc[2][8];
  #pragma unroll
  for (int mt = 0; mt < 2; ++mt)
    #pragma unroll
    for (int nt = 0; nt < 8; ++nt) {
      f32x4 z = {0.f, 0.f, 0.f, 0.f};
      acc[mt][nt] = z;
    }

  f16x8 ca[2], na[2];
  auto loadA = [&](int c, f16x8 (&A)[2]) {
    #pragma unroll
    for (int mt = 0; mt < 2; ++mt)
      A[mt] = *(const f16x8*)(w2f + (c * 8 + wv * 2 + mt) * 512 + mn * 32 + quad * 8);
  };
  loadA(0, ca);
  #pragma unroll
  for (int c = 0; c < 14; ++c) {
    if (c < 13) loadA(c + 1, na);
    const int tap = c >> 1;
    const int ch0 = (c & 1) * 32 + quad * 8;
    #pragma unroll
    for (int nt = 0; nt < 8; ++nt) {
      f16x8 bb = *(const f16x8*)(h1f + (nt * 16 + mn + tap) * 72 + ch0);
      acc[0][nt] = __builtin_amdgcn_mfma_f32_16x16x32_f16(ca[0], bb, acc[0][nt], 0, 0, 0);
      acc[1][nt] = __builtin_amdgcn_mfma_f32_16x16x32_f16(ca[1], bb, acc[1][nt], 0, 0, 0);
    }
    ca[0] = na[0]; ca[1] = na[1];
  }
  __syncthreads();   // h1f dead; reduction buffers alias

  #pragma unroll
  for (int mt = 0; mt < 2; ++mt)
    #pragma unroll
    for (int r = 0; r < 4; ++r) {
      int o = (wv * 2 + mt) * 16 + quad * 4 + r;
      float bo = b2c[o];
      float s = 0.f, ss = 0.f;
      #pragma unroll
      for (int nt = 0; nt < 8; ++nt) {
        float v = acc[mt][nt][r] + bo;
        s += v; ss += v * v;
      }
      redS[o * 17 + mn] = s;
      redSS[o * 17 + mn] = ss;
    }
  __syncthreads();
  {
    int o = threadIdx.x & 127;
    const float* src = (threadIdx.x < 128) ? redS : redSS;
    float s = 0.f;
    #pragma unroll
    for (int j = 0; j < 16; ++j) s += src[o * 17 + j];
    partials[blockIdx.x * 256 + threadIdx.x] = s;
  }
}

// ---------------------------------------------------------------------------
// Kernel 5: fp32 recompute of c2 head + bn2 + conv3(t=0) + tanh -> HRTF gather.
// ---------------------------------------------------------------------------
__global__ __launch_bounds__(256) void finalize_spatial(
    const float* __restrict__ x,
    const float* __restrict__ W1c, const float* __restrict__ b1c,
    const float* __restrict__ coef1,
    const float* __restrict__ W2c, const float* __restrict__ b2c,
    const float* __restrict__ coef2,
    const float* __restrict__ W3c, const float* __restrict__ b3c,
    const float* __restrict__ hrtf, float* __restrict__ wgbuf)
{
  __shared__ float xl[NB * 2 * 16];
  __shared__ float h1l[NB * 64 * 10];
  __shared__ float h2l[NB * NH2 * 4];
  __shared__ float sp[48];
  const int tid = threadIdx.x;
  {
    int bb = tid >> 5, i = (tid >> 4) & 1, j = tid & 15;
    int t = j - 6;
    xl[tid] = (t >= 0) ? x[(bb * 2 + i) * TLEN + t] : 0.f;
  }
  __syncthreads();
  for (int e = tid; e < NB * 64; e += 256) {
    int bb = e >> 6, ch = e & 63;
    float a1 = coef1[ch], d1 = coef1[64 + ch], bo = b1c[ch];
    for (int tt = 0; tt < 10; ++tt) {
      float acc = bo;
      #pragma unroll
      for (int i2 = 0; i2 < 2; ++i2)
        #pragma unroll
        for (int k = 0; k < 7; ++k)
          acc += xl[(bb * 2 + i2) * 16 + tt + k] * W1c[ch * 14 + i2 * 7 + k];
      float v = lrelu(a1 * acc + d1);
      h1l[(bb * 64 + ch) * 10 + tt] = (tt >= 3) ? v : 0.f;
    }
  }
  __syncthreads();
  for (int e = tid; e < NB * NH2; e += 256) {
    int bb = e >> 7, o = e & 127;
    float a2 = coef2[o], d2 = coef2[NH2 + o], bo = b2c[o];
    float acc[4] = {bo, bo, bo, bo};
    for (int i = 0; i < 64; ++i)
      #pragma unroll
      for (int k = 0; k < 7; ++k) {
        float w = W2c[(o * 64 + i) * 7 + k];
        #pragma unroll
        for (int t = 0; t < 4; ++t)
          acc[t] += h1l[(bb * 64 + i) * 10 + t + k] * w;
      }
    #pragma unroll
    for (int t = 0; t < 4; ++t)
      h2l[(bb * NH2 + o) * 4 + t] = lrelu(a2 * acc[t] + d2);
  }
  __syncthreads();
  if (tid < 48) {
    int bb = tid / 6, c3 = tid % 6;
    float acc = b3c[c3];
    for (int c = 0; c < NH2; ++c)
      #pragma unroll
      for (int k = 3; k < 7; ++k)
        acc += h2l[(bb * NH2 + c) * 4 + (k - 3)] * W3c[(c3 * NH2 + c) * 7 + k];
    sp[tid] = tanhf(acc);
  }
  __syncthreads();
  if (tid < 16) {
    int bb = tid >> 1, i = tid & 1;
    float az = (sp[bb * 6 + i * 3 + 0] + 1.f) * 0.5f * 11.f;
    float el = (sp[bb * 6 + i * 3 + 1] + 1.f) * 0.5f * 4.f;
    float dist = (sp[bb * 6 + i * 3 + 2] + 1.f) * 0.5f * 0.9f + 0.1f;
    int azi = min(max((int)az, 0), 11);
    int eli = min(max((int)el, 0), 4);
    int idx = eli * 12 + azi;
    for (int e = 0; e < 14; ++e)
      wgbuf[(bb * 2 + i) * 14 + e] = hrtf[idx * 14 + e] * dist;
  }
}

// ---------------------------------------------------------------------------
// Kernel 6: summed[b,c,t] = sum_{i,k} x[b,i,t+k-3] * wg[b,i,c,k]
// ---------------------------------------------------------------------------
__global__ __launch_bounds__(256) void mix_kernel(
    const float* __restrict__ x, const float* __restrict__ wgbuf,
    float* __restrict__ summed)
{
  const int b = blockIdx.x >> 7;
  const int t0 = (blockIdx.x & 127) * 1024 + threadIdx.x * 4;
  float wv[2][2][7];
  #pragma unroll
  for (int i = 0; i < 2; ++i)
    #pragma unroll
    for (int c = 0; c < 2; ++c)
      #pragma unroll
      for (int k = 0; k < 7; ++k)
        wv[i][c][k] = wgbuf[(b * 2 + i) * 14 + c * 7 + k];
  float acc[2][4] = {{0.f, 0.f, 0.f, 0.f}, {0.f, 0.f, 0.f, 0.f}};
  #pragma unroll
  for (int i = 0; i < 2; ++i) {
    float xl[12];
    #pragma unroll
    for (int j = 0; j < 12; ++j) {
      int tg = t0 - 4 + j;
      xl[j] = (tg >= 0 && tg < TLEN) ? x[(b * 2 + i) * TLEN + tg] : 0.f;
    }
    #pragma unroll
    for (int c = 0; c < 2; ++c)
      #pragma unroll
      for (int k = 0; k < 7; ++k)
        #pragma unroll
        for (int tt = 0; tt < 4; ++tt)
          acc[c][tt] += xl[tt + k + 1] * wv[i][c][k];
  }
  #pragma unroll
  for (int c = 0; c < 2; ++c)
    *reinterpret_cast<float4*>(&summed[(b * 2 + c) * TLEN + t0]) =
        make_float4(acc[c][0], acc[c][1], acc[c][2], acc[c][3]);
}

// ---------------------------------------------------------------------------
// Kernel 11: 120-col tile, grid (1093, NB). h1 fp16 -> conv2 MFMA (2 N-tiles
// per wave, 8 M-tiles in 4+4 halves, coalesced A) -> bn2+lrelu -> h2t fp16
// [col][ch] -> conv3 MFMA (K=ch) -> dq -> 7-tap gather + tanh.
// LDS 39,936 B; __launch_bounds__(256,4) caps VGPR at 128 -> 4 blocks/CU.
// ---------------------------------------------------------------------------
__global__ __launch_bounds__(256, 4) void conv2_final_mfma(
    const float* __restrict__ xin,
    const float* __restrict__ W1c, const float* __restrict__ b1c,
    const float* __restrict__ coef1,
    const unsigned short* __restrict__ w2f,
    const float* __restrict__ b2c, const float* __restrict__ coef2,
    const unsigned short* __restrict__ w3g, const float* __restrict__ rb3c,
    float* __restrict__ out)
{
  const int b  = blockIdx.y;
  const int t0 = blockIdx.x * FT;

  __shared__ __align__(16) char smem[39936];
  float* xs  = (float*)smem;                             // [2][168], j <-> t0-9+j
  float* w1T = (float*)(smem + 1344);                    // [14][64]
  unsigned short* h1f = (unsigned short*)(smem + 4928);  // [134][72], r <-> t0-6+r
  unsigned short* h2t = (unsigned short*)smem;           // [128][136] (late alias)
  unsigned short* dq  = (unsigned short*)(smem + 34816); // [128][20]

  stage_x_w1(t0, 9, xin, b, W1c, xs, w1T);
  __syncthreads();
  h1_compute<9, 134, 6>(t0, xs, w1T, coef1, b1c, h1f);
  __syncthreads();

  const int lane = threadIdx.x & 63;
  const int wv = threadIdx.x >> 6;
  const int mn = lane & 15, quad = lane >> 4;
  const int nt0 = wv * 2;

  // ---- conv2: 14 K-chunks x 2 N-tiles x (4+4) M-tiles per wave ----
  f32x4 acc[8][2];
  #pragma unroll
  for (int mt = 0; mt < 8; ++mt)
    #pragma unroll
    for (int i = 0; i < 2; ++i) {
      f32x4 z = {0.f, 0.f, 0.f, 0.f};
      acc[mt][i] = z;
    }

  #pragma unroll
  for (int c = 0; c < 14; ++c) {
    const int tap = c >> 1;
    const int ch0 = (c & 1) * 32 + quad * 8;
    f16x8 b0 = *(const f16x8*)(h1f + (nt0 * 16 + mn + tap) * 72 + ch0);
    f16x8 b1 = *(const f16x8*)(h1f + ((nt0 + 1) * 16 + mn + tap) * 72 + ch0);
    #pragma unroll
    for (int h = 0; h < 2; ++h) {
      f16x8 Ac[4];
      #pragma unroll
      for (int m = 0; m < 4; ++m)
        Ac[m] = *(const f16x8*)(w2f + (c * 8 + h * 4 + m) * 512 + mn * 32 + quad * 8);
      #pragma unroll
      for (int m = 0; m < 4; ++m) {
        acc[h * 4 + m][0] = __builtin_amdgcn_mfma_f32_16x16x32_f16(Ac[m], b0, acc[h * 4 + m][0], 0, 0, 0);
        acc[h * 4 + m][1] = __builtin_amdgcn_mfma_f32_16x16x32_f16(Ac[m], b1, acc[h * 4 + m][1], 0, 0, 0);
      }
    }
  }
  __syncthreads();   // h1f/xs/w1T dead; h2t aliases them

  // ---- bn2 + lrelu -> h2t fp16 [j'][ch]; j' <-> t = t0-3+j' ----
  #pragma unroll
  for (int i = 0; i < 2; ++i) {
    int jp = (nt0 + i) * 16 + mn;
    int t = t0 - 3 + jp;
    bool ok = (t >= 0) && (t < TLEN);
    #pragma unroll
    for (int mt = 0; mt < 8; ++mt) {
      unsigned us[4];
      #pragma unroll
      for (int r = 0; r < 4; ++r) {
        int o = mt * 16 + quad * 4 + r;
        float v = acc[mt][i][r] + b2c[o];
        v = lrelu(coef2[o] * v + coef2[NH2 + o]);
        us[r] = h16(ok ? v : 0.f);
      }
      *(uint2*)(h2t + jp * 136 + mt * 16 + quad * 4) =
          make_uint2(us[0] | (us[1] << 16), us[2] | (us[3] << 16));
    }
  }
  __syncthreads();

  // ---- conv3: D'[m=oc*7+tap][n=j'] = sum_ch W3 * h2 ----
  f32x4 acc3[2];
  #pragma unroll
  for (int i = 0; i < 2; ++i) {
    f32x4 z = {0.f, 0.f, 0.f, 0.f};
    acc3[i] = z;
  }
  #pragma unroll
  for (int c = 0; c < 4; ++c) {
    f16x8 A3 = *(const f16x8*)(w3g + c * 512 + mn * 32 + quad * 8);
    #pragma unroll
    for (int i = 0; i < 2; ++i) {
      f16x8 bb = *(const f16x8*)(h2t + ((nt0 + i) * 16 + mn) * 136 + c * 32 + quad * 8);
      acc3[i] = __builtin_amdgcn_mfma_f32_16x16x32_f16(A3, bb, acc3[i], 0, 0, 0);
    }
  }
  #pragma unroll
  for (int i = 0; i < 2; ++i) {
    int n = (nt0 + i) * 16 + mn;
    unsigned us[4];
    #pragma unroll
    for (int r = 0; r < 4; ++r) us[r] = h16(acc3[i][r]);
    *(uint2*)(dq + n * 20 + quad * 4) =
        make_uint2(us[0] | (us[1] << 16), us[2] | (us[3] << 16));
  }
  __syncthreads();

  // ---- gather: out[oc][u] = tanh(b3 + sum_tap D'[u+tap][oc*7+tap]) ----
  {
    int tid = threadIdx.x;
    if (tid < 240) {
      int oc = (tid >= FT) ? 1 : 0;
      int u = tid - oc * FT;
      float s = rb3c[oc];
      #pragma unroll
      for (int tap = 0; tap < 7; ++tap)
        s += fh16(dq[(u + tap) * 20 + oc * 7 + tap]);
      int t = t0 + u;
      if (t < TLEN) out[(b * 2 + oc) * TLEN + t] = tanhf(s);
    }
  }
}

// ---------------------------------------------------------------------------
extern "C" void kernel_launch(void* const* d_in, const int* in_sizes, int n_in,
                              void* d_out, int out_size, void* d_ws, size_t ws_size,
                              hipStream_t stream)
{
  (void)in_sizes; (void)n_in; (void)out_size; (void)ws_size;
  const float* x    = (const float*)d_in[0];
  const float* W1   = (const float*)d_in[1];
  const float* b1   = (const float*)d_in[2];
  const float* g1   = (const float*)d_in[3];
  const float* be1  = (const float*)d_in[4];
  const float* W2   = (const float*)d_in[5];
  const float* b2   = (const float*)d_in[6];
  const float* g2   = (const float*)d_in[7];
  const float* be2  = (const float*)d_in[8];
  const float* W3   = (const float*)d_in[9];
  const float* b3   = (const float*)d_in[10];
  const float* hrtf = (const float*)d_in[11];
  const float* RW1  = (const float*)d_in[12];
  const float* rb1  = (const float*)d_in[13];
  const float* rg1  = (const float*)d_in[14];
  const float* rbe1 = (const float*)d_in[15];
  const float* RW2  = (const float*)d_in[16];
  const float* rb2  = (const float*)d_in[17];
  const float* rg2  = (const float*)d_in[18];
  const float* rbe2 = (const float*)d_in[19];
  const float* RW3  = (const float*)d_in[20];
  const float* rb3  = (const float*)d_in[21];
  float* out = (float*)d_out;

  // d_out doubles as the 8192x256-f stats-partials buffer (lifetime ends
  // before conv2_final_mfma writes output).
  float* partialsB = (float*)d_out;

  char* ws = (char*)d_ws;
  float* partialsA      = (float*)(ws + 0);        // 524,288 B
  float* summed         = (float*)(ws + 524288);   // 8,388,608 B
  float* coef1          = (float*)(ws + 8912896);  // 128 f
  float* coef2          = (float*)(ws + 8913408);  // 256 f
  float* coefR1         = (float*)(ws + 8914432);  // 128 f
  float* coefR2         = (float*)(ws + 8914944);  // 256 f
  float* wgbuf          = (float*)(ws + 8915968);  // 224 f
  unsigned short* w2sp  = (unsigned short*)(ws + 8916992);  // 114,688 B
  unsigned short* w2re  = (unsigned short*)(ws + 9031680);  // 114,688 B
  unsigned short* w3g   = (unsigned short*)(ws + 9146368);  // 4,096 B
  // total ws use: 9,150,464 bytes

  prep_weights<<<456, 256, 0, stream>>>(W2, RW2, RW3, w2sp, w2re, w3g);
  // ---- spatial parameter network ----
  conv1_stats<<<1024, 256, 0, stream>>>(x, W1, b1, partialsA);
  reduce_coef<<<64, 256, 0, stream>>>(partialsA, 1024, 64, g1, be1, coef1);
  conv2_stats_mfma<<<8192, 256, 0, stream>>>(x, W1, b1, coef1, w2sp, b2, partialsB);
  reduce_coef<<<128, 256, 0, stream>>>(partialsB, 8192, 128, g2, be2, coef2);
  finalize_spatial<<<1, 256, 0, stream>>>(x, W1, b1, coef1, W2, b2, coef2,
                                          W3, b3, hrtf, wgbuf);
  // ---- HRTF mixing ----
  mix_kernel<<<1024, 256, 0, stream>>>(x, wgbuf, summed);
  // ---- binaural renderer ----
  conv1_stats<<<1024, 256, 0, stream>>>(summed, RW1, rb1, partialsA);
  reduce_coef<<<64, 256, 0, stream>>>(partialsA, 1024, 64, rg1, rbe1, coefR1);
  conv2_stats_mfma<<<8192, 256, 0, stream>>>(summed, RW1, rb1, coefR1,
                                             w2re, rb2, partialsB);
  reduce_coef<<<128, 256, 0, stream>>>(partialsB, 8192, 128, rg2, rbe2, coefR2);
  conv2_final_mfma<<<dim3(FGRID, NB), 256, 0, stream>>>(
      summed, RW1, rb1, coefR1, w2re, rb2, coefR2, w3g, rb3, out);
}